// Round 19
// baseline (7017.725 us; speedup 1.0000x reference)
//
#include <hip/hip_runtime.h>
#include <cstdint>

typedef short bf16x8 __attribute__((ext_vector_type(8)));
typedef float f32x4 __attribute__((ext_vector_type(4)));

#define MFMA(a,b,c) __builtin_amdgcn_mfma_f32_16x16x32_bf16((a),(b),(c),0,0,0)

// ---------------- ws layout (bytes) ----------------
constexpr size_t OP2   = 0;                                  // P2 bf16 frags [512rt][42nt][64][4]
constexpr size_t SZP2  = (size_t)512*42*512;                 // 11,010,048
constexpr size_t OWSUM = OP2 + SZP2;                         // [25ks][42nt][512] bf16
constexpr size_t SZWSUM= (size_t)25*42*512*2;
constexpr size_t OWEAM = OWSUM + SZWSUM;                     // enc A-side mu [28][21][512]
constexpr size_t SZWEA = (size_t)28*21*512*2;
constexpr size_t OWEAL = OWEAM + SZWEA;
constexpr size_t OWEBM = OWEAL + SZWEA;                      // enc h-side [4][21][512]
constexpr size_t SZWEB = (size_t)4*21*512*2;
constexpr size_t OWEBL = OWEBM + SZWEB;
constexpr size_t OWH   = OWEBL + SZWEB;                      // heads [8][14][512]
constexpr size_t SZWH  = (size_t)8*14*512*2;
constexpr size_t OWD   = OWH + SZWH;                         // dec [8][21][512]
constexpr size_t SZWD  = (size_t)8*21*512*2;
constexpr size_t OWW   = OWD + SZWD;                         // write [4][49][512]
constexpr size_t SZWW  = (size_t)4*49*512*2;
constexpr size_t OBP2  = OWW + SZWW;                         // f32 bias frags
constexpr size_t OBGHN = OBP2 + (size_t)42*256*4;
constexpr size_t OBDI  = OBGHN + (size_t)2*7*256*4;
constexpr size_t OBDHN = OBDI + (size_t)21*256*4;
constexpr size_t OBWR  = OBDHN + (size_t)7*256*4;
constexpr size_t OBH   = OBWR + (size_t)49*256*4;
constexpr size_t OGH   = OBH + (size_t)14*256*4;             // Ghml bf16 [8192][256] (hmu|hlv padded)
constexpr size_t OGD   = OGH + (size_t)8192*512;             // Ghdec bf16 [8192][112]
constexpr size_t WSEND = OGD + (size_t)8192*224;             // ~20.1 MB

__device__ __forceinline__ float sigf(float x){ return 1.0f/(1.0f+__expf(-x)); }
__device__ __forceinline__ float tanhfast(float x){ return 1.0f - 2.0f/(__expf(2.0f*x)+1.0f); }
__device__ __forceinline__ float bf2f(unsigned short u){ return __uint_as_float(((unsigned int)u)<<16); }
__device__ __forceinline__ unsigned short f2bf(float f){ unsigned int x = __float_as_uint(f); return (unsigned short)((x + 0x8000u) >> 16); }

// ---------------- weight / bias packing + state zero ----------------
__global__ void init_pack(
    const float* __restrict__ ihmu, const float* __restrict__ whhmu,
    const float* __restrict__ bihmu, const float* __restrict__ bhhmu,
    const float* __restrict__ ihlv, const float* __restrict__ whhlv,
    const float* __restrict__ bihlv, const float* __restrict__ bhhlv,
    const float* __restrict__ wmu, const float* __restrict__ bmu,
    const float* __restrict__ wlv, const float* __restrict__ blv,
    const float* __restrict__ ihd, const float* __restrict__ whhd,
    const float* __restrict__ bihd, const float* __restrict__ bhhd,
    const float* __restrict__ wwr, const float* __restrict__ bwr,
    char* __restrict__ wsb)
{
  int u = blockIdx.x*256 + threadIdx.x;
  if (u < 1469440) {
    int v = u; size_t off; int NT; int region;
    if      (v < 537600)            { region=0; off=OWSUM; NT=42; }
    else if ((v-=537600) < 301056)  { region=1; off=OWEAM; NT=21; }
    else if ((v-=301056) < 301056)  { region=2; off=OWEAL; NT=21; }
    else if ((v-=301056) < 43008)   { region=3; off=OWEBM; NT=21; }
    else if ((v-=43008)  < 43008)   { region=4; off=OWEBL; NT=21; }
    else if ((v-=43008)  < 57344)   { region=5; off=OWH;   NT=14; }
    else if ((v-=57344)  < 86016)   { region=6; off=OWD;   NT=21; }
    else    { v-=86016;   region=7; off=OWW;   NT=49; }
    int ks = v / (NT*512); int rem = v - ks*(NT*512);
    int nt = rem >> 9; int li = rem & 511;
    int l = li >> 3, e = li & 7;
    int k = ks*32 + ((l>>4)<<3) + e;
    int c = l & 15;
    float val = 0.f;
    if (region==0) {
      int gru = nt/21, ntg = nt%21, gate = ntg/7, j = (ntg%7)*16 + c;
      if (j<100 && k<784) { const float* IH = gru? ihlv : ihmu; int jj = gate*100+j;
        val = IH[(size_t)jj*1668 + k] + IH[(size_t)jj*1668 + 784 + k]; }
    } else if (region==1 || region==2) {
      const float* IH = (region==2)? ihlv : ihmu;
      int gate = nt/7, j = (nt%7)*16 + c;
      if (j<100) { int jj = gate*100+j;
        if (k<784)      val = -IH[(size_t)jj*1668 + 784 + k];
        else if (k<884) val =  IH[(size_t)jj*1668 + 1568 + (k-784)]; }
    } else if (region==3 || region==4) {
      const float* WHH = (region==4)? whhlv : whhmu;
      int gate = nt/7, j = (nt%7)*16 + c;
      if (j<100 && k<100) val = WHH[(gate*100+j)*100 + k];
    } else if (region==5) {
      int grp = nt/7, j = (nt%7)*16 + c;
      if (j<100) {
        if (grp==0) { if (k<100) val = wmu[j*100+k]; }
        else        { if (k>=128 && k<228) val = wlv[j*100 + (k-128)]; }
      }
    } else if (region==6) {
      int gate = nt/7, j = (nt%7)*16 + c;
      if (j<100) { int jj = gate*100+j;
        if (k<100)               val = ihd[jj*100+k];
        else if (k>=128 && k<228) val = whhd[jj*100 + (k-128)]; }
    } else {
      int n = nt*16 + c;
      if (k<100) val = wwr[n*100+k];
    }
    *(unsigned short*)(wsb + off + (size_t)v*2) = f2bf(val);
    return;
  }
  u -= 1469440;
  if (u >= 37632) {
    int u2 = u - 37632;                     // zero Ghml + Ghdec (1,507,328 words)
    if (u2 < 1507328) *(float*)(wsb + OGH + (size_t)u2*4) = 0.f;
    return;
  }
  float val = 0.f; size_t off; int v = u;
  if (v < 10752) { off = OBP2;
    int nt = v>>8, li = v&255, l = li>>2, c = l&15;
    int gru = nt/21, ntg = nt%21, gate = ntg/7, j = (ntg%7)*16 + c;
    if (j<100) {
      const float* BI = gru? bihlv : bihmu; const float* BH = gru? bhhlv : bhhmu;
      val = BI[gate*100+j] + ((gate<2)? BH[gate*100+j] : 0.f);
    }
  } else if ((v-=10752) < 3584) { off = OBGHN;
    int g = v/1792, r2 = v - g*1792, pp = r2>>8, li = r2&255, l = li>>2, c = l&15;
    int j = pp*16+c;
    if (j<100) val = (g? bhhlv : bhhmu)[200+j];
  } else if ((v-=3584) < 5376) { off = OBDI;
    int nt = v>>8, li = v&255, l = li>>2, c = l&15;
    int gate = nt/7, j = (nt%7)*16+c;
    if (j<100) val = (gate<2)? (bihd[gate*100+j]+bhhd[gate*100+j]) : bihd[200+j];
  } else if ((v-=5376) < 1792) { off = OBDHN;
    int pp = v>>8, li = v&255, l = li>>2, c = l&15; int j = pp*16+c;
    if (j<100) val = bhhd[200+j];
  } else if ((v-=1792) < 12544) { off = OBWR;
    int nt = v>>8, li = v&255, l = li>>2, c = l&15;
    val = bwr[nt*16+c];
  } else { v -= 12544; off = OBH;
    int nt = v>>8, li = v&255, l = li>>2, c = l&15;
    int grp = nt/7, j = (nt%7)*16+c;
    if (j<100) val = grp? blv[j] : bmu[j];
  }
  *(float*)(wsb + off + (size_t)v*4) = val;
}

// zero canvas c (accumulated in out_c across 2-step launches)
__global__ void init_out(float* __restrict__ out)
{
  size_t i = (size_t)blockIdx.x*1024 + threadIdx.x;
  if (i < (size_t)8192*784) out[i] = 0.f;
}

// ---------------- P2 = x@(W1+W2)^T + bias -> bf16 fragments ----------------
__global__ __launch_bounds__(512) void init_p2(const float* __restrict__ x, char* __restrict__ wsb)
{
  __shared__ char xt[16*1600];
  const int tid = threadIdx.x, l = tid&63, w = tid>>6;
  const int lr = l&15, lg = l>>4;
  const int rt = blockIdx.x;
  for (int i = tid; i < 16*800; i += 512) {
    int row = i/800, col = i - row*800;
    unsigned short hv = 0;
    if (col < 784) hv = f2bf(x[(size_t)(rt*16+row)*784 + col]);
    *(unsigned short*)(xt + ((row*1600 + col*2) ^ ((row&7)<<4))) = hv;
  }
  __syncthreads();
  const char* WS = wsb + OWSUM;
  for (int nt = w; nt < 42; nt += 8) {
    f32x4 acc = *(const f32x4*)(wsb + OBP2 + (size_t)(nt*256 + l*4)*4);
    const char* wp = WS + (size_t)(nt*512 + l*8)*2;
    #pragma unroll 5
    for (int ks = 0; ks < 25; ++ks) {
      bf16x8 a = *(const bf16x8*)(xt + ((lr*1600 + ks*64 + lg*16) ^ ((lr&7)<<4)));
      bf16x8 b = *(const bf16x8*)(wp + (size_t)ks*42*512*2);
      acc = MFMA(a,b,acc);
    }
    ushort4 ov; ov.x=f2bf(acc[0]); ov.y=f2bf(acc[1]); ov.z=f2bf(acc[2]); ov.w=f2bf(acc[3]);
    *(ushort4*)(wsb + OP2 + ((size_t)(rt*42+nt)*64 + l)*8) = ov;
  }
}

// ------- 2-step kernel: 512 blocks x 1024 threads (16 waves), 16 rows, t0 and t0+1 -------
__global__ __launch_bounds__(1024,8) void draw_step2(
    const float* __restrict__ noise, char* __restrict__ wsb, float* __restrict__ out, int t0)
{
  extern __shared__ char sm[];
  char* Aenc = sm;               // [16][1792 B] bf16: sigc(784) | hdec(100) | pad
  char* Ahml = sm + 28672;       // [16][512 B]  bf16: hmu(100) pad | hlv(100) pad
  char* Adec = sm + 36864;       // [16][512 B]  bf16: z(100) pad | hdec(100) pad
  float* muv = (float*)(sm + 45056);   // [1600] mu | [1600] lv (f32)

  const int tid = threadIdx.x, l = tid&63, w = tid>>6;   // w in [0,16)
  const int lr = l&15, lg = l>>4;
  const int blk = blockIdx.x;

  float* out_c  = out;
  float* out_mu = out + (size_t)8192*784;
  float* out_lv = out_mu + (size_t)32*8192*100;

  // ===== phase 0: load state from global =====
  {
    const float* cb = out_c + (size_t)blk*16*784;
    for (int i = tid; i < 16*98; i += 1024) {
      int row = i/98, cc = i - row*98;
      f32x4 v0 = *(const f32x4*)(cb + (size_t)row*784 + cc*8);
      f32x4 v1 = *(const f32x4*)(cb + (size_t)row*784 + cc*8 + 4);
      unsigned short h[8];
      h[0]=f2bf(sigf(v0[0])); h[1]=f2bf(sigf(v0[1])); h[2]=f2bf(sigf(v0[2])); h[3]=f2bf(sigf(v0[3]));
      h[4]=f2bf(sigf(v1[0])); h[5]=f2bf(sigf(v1[1])); h[6]=f2bf(sigf(v1[2])); h[7]=f2bf(sigf(v1[3]));
      *(bf16x8*)(Aenc + ((row*1792 + cc*16) ^ ((row&7)<<4))) = *(bf16x8*)h;
    }
    // hdec chunks: into Aenc cols 784+ AND Adec bytes 256+
    for (int i = tid; i < 16*14; i += 1024) {
      int row = i/14, cc = i - row*14;
      f32x4 v = *(const f32x4*)(wsb + OGD + (size_t)(blk*16+row)*224 + cc*16);
      *(f32x4*)(Aenc + ((row*1792 + (98+cc)*16) ^ ((row&7)<<4))) = v;
      *(f32x4*)(Adec + ((row*512 + 256 + cc*16) ^ ((row&7)<<4))) = v;
    }
    // hml from Ghml
    for (int i = tid; i < 16*32; i += 1024) {
      int row = i/32, cc = i - row*32;
      f32x4 v = *(const f32x4*)(wsb + OGH + (size_t)(blk*16+row)*512 + cc*16);
      *(f32x4*)(Ahml + ((row*512 + cc*16) ^ ((row&7)<<4))) = v;
    }
    // zero Adec z-region (bytes 0..255) + tail chunks (bytes 480..511)
    const f32x4 zz = {0.f,0.f,0.f,0.f};
    for (int i = tid; i < 16*16; i += 1024) {
      int row = i/16, cc = i - row*16;
      *(f32x4*)(Adec + ((row*512 + cc*16) ^ ((row&7)<<4))) = zz;
    }
    for (int i = tid; i < 16*2; i += 1024) {
      int row = i/2, cc = 30 + (i&1);
      *(f32x4*)(Adec + ((row*512 + cc*16) ^ ((row&7)<<4))) = zz;
    }
  }

  const bool isMu = (w < 7);
  const bool isLv = (w >= 8 && w < 15);
  const bool act  = isMu || isLv;
  const int p = isMu ? w : (w - 8);
  const int axor = (lr&7)<<4;

  const f32x4 z4 = {0.f,0.f,0.f,0.f};

  // canvas fragments in registers across both steps
  f32x4 creg[4] = {z4,z4,z4,z4};
  #pragma unroll
  for (int rep=0; rep<4; ++rep) {
    int nt = w + rep*16;
    if (nt < 49) {
      #pragma unroll
      for (int e=0;e<4;++e)
        creg[rep][e] = out_c[(size_t)(blk*16 + lg*4 + e)*784 + nt*16 + lr];
    }
  }
  __syncthreads();                         // B0: state staged

  for (int it = 0; it < 2; ++it) {
    const int t = t0 + it;

    // ---- noise prefetch ----
    float noz[2] = {0.f, 0.f};
    #pragma unroll
    for (int k2=0;k2<2;++k2) {
      int i = tid + k2*1024;
      if (i < 1600)
        noz[k2] = __builtin_nontemporal_load(noise + (size_t)t*819200 + (size_t)blk*1600 + i);
    }

    // ===== encoder GEMM =====
    f32x4 ar=z4, az=z4, an=z4, ahn=z4;
    if (act) {
      size_t pb = OP2 + (((size_t)blk*42 + (isLv?21:0) + p)*64 + l)*8;
      ushort4 pr = *(const ushort4*)(wsb + pb);
      ushort4 pz = *(const ushort4*)(wsb + pb + (size_t)7*64*8);
      ushort4 pn = *(const ushort4*)(wsb + pb + (size_t)14*64*8);
      ar[0]=bf2f(pr.x); ar[1]=bf2f(pr.y); ar[2]=bf2f(pr.z); ar[3]=bf2f(pr.w);
      az[0]=bf2f(pz.x); az[1]=bf2f(pz.y); az[2]=bf2f(pz.z); az[3]=bf2f(pz.w);
      an[0]=bf2f(pn.x); an[1]=bf2f(pn.y); an[2]=bf2f(pn.z); an[3]=bf2f(pn.w);
      ahn = *(const f32x4*)(wsb + OBGHN + (size_t)(((isLv?7:0)+p)*256 + l*4)*4);
      const char* wr = wsb + (isLv? OWEAL : OWEAM) + (size_t)(p*512 + l*8)*2;
      const char* wz = wr + (size_t)7*512*2;
      const char* wn = wr + (size_t)14*512*2;
      int abase = lr*1792 + lg*16;
      #pragma unroll 4
      for (int ks=0; ks<28; ++ks) {
        bf16x8 a = *(const bf16x8*)(Aenc + ((abase + ks*64) ^ axor));
        size_t so = (size_t)ks*21*512*2;
        ar = MFMA(a, *(const bf16x8*)(wr+so), ar);
        az = MFMA(a, *(const bf16x8*)(wz+so), az);
        an = MFMA(a, *(const bf16x8*)(wn+so), an);
      }
      const char* vr = wsb + (isLv? OWEBL : OWEBM) + (size_t)(p*512 + l*8)*2;
      const char* vz = vr + (size_t)7*512*2;
      const char* vn = vr + (size_t)14*512*2;
      int hb = lr*512 + (isLv?256:0) + lg*16;
      #pragma unroll
      for (int ks=0; ks<4; ++ks) {
        bf16x8 a = *(const bf16x8*)(Ahml + ((hb + ks*64) ^ axor));
        size_t so = (size_t)ks*21*512*2;
        ar  = MFMA(a, *(const bf16x8*)(vr+so), ar);
        az  = MFMA(a, *(const bf16x8*)(vz+so), az);
        ahn = MFMA(a, *(const bf16x8*)(vn+so), ahn);
      }
    }
    __syncthreads();                       // B1: Ahml reads done
    if (act) {
      int col = p*16 + lr;
      #pragma unroll
      for (int e=0;e<4;++e) {
        float rg = sigf(ar[e]);
        float zg = sigf(az[e]);
        float nn = tanhfast(fmaf(rg, ahn[e], an[e]));
        int row = lg*4 + e;
        if (col < 100) {
          size_t ha = (size_t)((row*512 + ((isLv?128:0)+col)*2) ^ ((row&7)<<4));
          float hold = bf2f(*(unsigned short*)(Ahml + ha));
          float hnew = nn + zg*(hold - nn);
          *(unsigned short*)(Ahml + ha) = f2bf(hnew);
        }
      }
    }
    __syncthreads();                       // B2: hmu/hlv ready

    // ===== heads =====
    if (isMu) {
      f32x4 am = *(const f32x4*)(wsb + OBH + (size_t)(p*256 + l*4)*4);
      const char* WH = wsb + OWH;
      int hb = lr*512 + lg*16;
      #pragma unroll
      for (int ks=0; ks<4; ++ks) {
        bf16x8 a0 = *(const bf16x8*)(Ahml + ((hb + ks*64) ^ axor));
        am = MFMA(a0, *(const bf16x8*)(WH + ((size_t)(ks*14+p)*512 + l*8)*2), am);
      }
      int col = p*16 + lr;
      if (col < 100) {
        #pragma unroll
        for (int e=0;e<4;++e)
          muv[(lg*4+e)*100 + col] = fmaxf(am[e], 0.f);
      }
    } else if (isLv) {
      f32x4 al = *(const f32x4*)(wsb + OBH + (size_t)((7+p)*256 + l*4)*4);
      const char* WH = wsb + OWH;
      int hb = lr*512 + 256 + lg*16;
      #pragma unroll
      for (int ks=0; ks<4; ++ks) {
        bf16x8 a1 = *(const bf16x8*)(Ahml + ((hb + ks*64) ^ axor));
        al = MFMA(a1, *(const bf16x8*)(WH + ((size_t)((ks+4)*14+7+p)*512 + l*8)*2), al);
      }
      int col = p*16 + lr;
      if (col < 100) {
        #pragma unroll
        for (int e=0;e<4;++e)
          muv[1600 + (lg*4+e)*100 + col] = fmaxf(al[e], 0.f);
      }
    }
    __syncthreads();                       // B3: muv complete

    // ===== z + mu/lv stores =====
    #pragma unroll
    for (int k2=0;k2<2;++k2) {
      int i = tid + k2*1024;
      if (i < 1600) {
        float m  = muv[i];
        float lv = muv[1600 + i];
        float zz = fmaf(noz[k2], __expf(0.5f*lv), m);
        int row = i/100, col = i - row*100;
        *(unsigned short*)(Adec + ((row*512 + col*2) ^ ((row&7)<<4))) = f2bf(zz);
      }
    }
    {
      size_t mb = (size_t)t*819200 + (size_t)blk*1600;
      if (tid < 800) {
        bool m0 = tid < 400;
        int k = m0 ? tid : tid - 400;
        f32x4 v = ((const f32x4*)muv)[tid];
        *((f32x4*)((m0 ? out_mu : out_lv) + mb) + k) = v;
      }
    }
    __syncthreads();                       // B4: Adec z ready

    // ===== decoder GRU =====
    f32x4 dr=z4, dz=z4, dn=z4, dhn=z4;
    if (isLv) {
      dr  = *(const f32x4*)(wsb + OBDI  + (size_t)(p*256 + l*4)*4);
      dz  = *(const f32x4*)(wsb + OBDI  + (size_t)((p+7)*256 + l*4)*4);
      dn  = *(const f32x4*)(wsb + OBDI  + (size_t)((p+14)*256 + l*4)*4);
      dhn = *(const f32x4*)(wsb + OBDHN + (size_t)(p*256 + l*4)*4);
      const char* br = wsb + OWD + (size_t)(p*512 + l*8)*2;
      const char* bz = br + (size_t)7*512*2;
      const char* bn = br + (size_t)14*512*2;
      int abase = lr*512 + lg*16;
      #pragma unroll
      for (int ks=0; ks<8; ++ks) {
        bf16x8 a = *(const bf16x8*)(Adec + ((abase + ks*64) ^ axor));
        size_t so = (size_t)ks*21*512*2;
        dr = MFMA(a, *(const bf16x8*)(br+so), dr);
        dz = MFMA(a, *(const bf16x8*)(bz+so), dz);
        if (ks<4) dn  = MFMA(a, *(const bf16x8*)(bn+so), dn);
        else      dhn = MFMA(a, *(const bf16x8*)(bn+so), dhn);
      }
    }
    __syncthreads();                       // B5: Adec reads done
    if (isLv) {
      int col = p*16 + lr;
      #pragma unroll
      for (int e=0;e<4;++e) {
        float rg = sigf(dr[e]);
        float zg = sigf(dz[e]);
        float nn = tanhfast(fmaf(rg, dhn[e], dn[e]));
        int row = lg*4 + e;
        if (col < 100) {
          float hold = bf2f(*(unsigned short*)(Aenc + ((row*1792 + (784+col)*2) ^ ((row&7)<<4))));
          float hnew = nn + zg*(hold - nn);
          unsigned short hb2 = f2bf(hnew);
          *(unsigned short*)(Adec + ((row*512 + (128+col)*2) ^ ((row&7)<<4))) = hb2;
          *(unsigned short*)(Aenc + ((row*1792 + (784+col)*2) ^ ((row&7)<<4))) = hb2;
        }
      }
    }
    __syncthreads();                       // B6: new hdec visible

    // ===== canvas write GEMM: accumulate creg; stage sigc to LDS (it=0) / out (t=31) =====
    {
      const char* WW = wsb + OWW;
      #pragma unroll
      for (int rep=0; rep<4; ++rep) {
        int nt = w + rep*16;
        if (nt < 49) {
          f32x4 c = z4;
          int abase = lr*512 + 256 + lg*16;
          #pragma unroll
          for (int ks=0; ks<4; ++ks) {
            bf16x8 a = *(const bf16x8*)(Adec + ((abase + ks*64) ^ axor));
            c = MFMA(a, *(const bf16x8*)(WW + ((size_t)(ks*49+nt)*512 + l*8)*2), c);
          }
          f32x4 bw = *(const f32x4*)(wsb + OBWR + (size_t)(nt*256 + l*4)*4);
          #pragma unroll
          for (int e=0;e<4;++e) {
            float cnew = creg[rep][e] + c[e] + bw[e];
            creg[rep][e] = cnew;
            int orow = lg*4 + e;
            int col = nt*16 + lr;
            if (t == 31) {
              out_c[(size_t)(blk*16+orow)*784 + col] = sigf(cnew);
            } else if (it == 0) {
              *(unsigned short*)(Aenc + ((orow*1792 + col*2) ^ ((orow&7)<<4))) = f2bf(sigf(cnew));
            }
          }
        }
      }
    }
    __syncthreads();                       // B7: sigc/states ready for next step
  }

  // ===== epilogue: persist state for next launch (t0 < 30) =====
  if (t0 < 30) {
    for (int i = tid; i < 16*32; i += 1024) {
      int row = i/32, cc = i - row*32;
      *(f32x4*)(wsb + OGH + (size_t)(blk*16+row)*512 + cc*16) =
        *(const f32x4*)(Ahml + ((row*512 + cc*16) ^ ((row&7)<<4)));
    }
    for (int i = tid; i < 16*14; i += 1024) {
      int row = i/14, cc = i - row*14;
      *(f32x4*)(wsb + OGD + (size_t)(blk*16+row)*224 + cc*16) =
        *(const f32x4*)(Aenc + ((row*1792 + (98+cc)*16) ^ ((row&7)<<4)));
    }
    #pragma unroll
    for (int rep=0; rep<4; ++rep) {
      int nt = w + rep*16;
      if (nt < 49) {
        #pragma unroll
        for (int e=0;e<4;++e)
          out_c[(size_t)(blk*16 + lg*4 + e)*784 + nt*16 + lr] = creg[rep][e];
      }
    }
  }
}

extern "C" void kernel_launch(void* const* d_in, const int* in_sizes, int n_in,
                              void* d_out, int out_size, void* d_ws, size_t ws_size,
                              hipStream_t stream) {
  (void)in_sizes; (void)n_in; (void)out_size; (void)ws_size;
  const float* x      = (const float*)d_in[0];
  const float* noise  = (const float*)d_in[1];
  const float* ih_mu  = (const float*)d_in[2];
  const float* whh_mu = (const float*)d_in[3];
  const float* bih_mu = (const float*)d_in[4];
  const float* bhh_mu = (const float*)d_in[5];
  const float* ih_lv  = (const float*)d_in[6];
  const float* whh_lv = (const float*)d_in[7];
  const float* bih_lv = (const float*)d_in[8];
  const float* bhh_lv = (const float*)d_in[9];
  const float* wmu    = (const float*)d_in[10];
  const float* bmu    = (const float*)d_in[11];
  const float* wlv    = (const float*)d_in[12];
  const float* blv    = (const float*)d_in[13];
  const float* wih_dec= (const float*)d_in[14];
  const float* whh_dec= (const float*)d_in[15];
  const float* bih_dec= (const float*)d_in[16];
  const float* bhh_dec= (const float*)d_in[17];
  const float* wwrite = (const float*)d_in[18];
  const float* bwrite = (const float*)d_in[19];
  char* wsb = (char*)d_ws;
  float* out = (float*)d_out;

  (void)hipFuncSetAttribute(reinterpret_cast<const void*>(draw_step2),
                            hipFuncAttributeMaxDynamicSharedMemorySize, 57856);

  init_pack<<<11775, 256, 0, stream>>>(ih_mu, whh_mu, bih_mu, bhh_mu,
                                       ih_lv, whh_lv, bih_lv, bhh_lv,
                                       wmu, bmu, wlv, blv,
                                       wih_dec, whh_dec, bih_dec, bhh_dec,
                                       wwrite, bwrite, wsb);
  init_out<<<6272, 1024, 0, stream>>>(out);
  init_p2<<<512, 512, 0, stream>>>(x, wsb);
  for (int t0 = 0; t0 < 32; t0 += 2)
    draw_step2<<<512, 1024, 57856, stream>>>(noise, wsb, out, t0);
}

// Round 20
// 6411.159 us; speedup vs baseline: 1.0946x; 1.0946x over previous
//
#include <hip/hip_runtime.h>
#include <cstdint>

typedef short bf16x8 __attribute__((ext_vector_type(8)));
typedef float f32x4 __attribute__((ext_vector_type(4)));

#define MFMA(a,b,c) __builtin_amdgcn_mfma_f32_16x16x32_bf16((a),(b),(c),0,0,0)

// ---------------- ws layout (bytes) ----------------
constexpr size_t OP2   = 0;                                  // P2 bf16 frags [512rt][42nt][64][4]
constexpr size_t SZP2  = (size_t)512*42*512;                 // 11,010,048
constexpr size_t OWSUM = OP2 + SZP2;                         // [25ks][42nt][512] bf16
constexpr size_t SZWSUM= (size_t)25*42*512*2;
constexpr size_t OWEAM = OWSUM + SZWSUM;                     // enc A-side mu [28][21][512]
constexpr size_t SZWEA = (size_t)28*21*512*2;
constexpr size_t OWEAL = OWEAM + SZWEA;
constexpr size_t OWEBM = OWEAL + SZWEA;                      // enc h-side [4][21][512]
constexpr size_t SZWEB = (size_t)4*21*512*2;
constexpr size_t OWEBL = OWEBM + SZWEB;
constexpr size_t OWH   = OWEBL + SZWEB;                      // heads [8][14][512]
constexpr size_t SZWH  = (size_t)8*14*512*2;
constexpr size_t OWD   = OWH + SZWH;                         // dec [8][21][512]
constexpr size_t SZWD  = (size_t)8*21*512*2;
constexpr size_t OWW   = OWD + SZWD;                         // write [4][49][512]
constexpr size_t SZWW  = (size_t)4*49*512*2;
constexpr size_t OBP2  = OWW + SZWW;                         // f32 bias frags
constexpr size_t OBGHN = OBP2 + (size_t)42*256*4;
constexpr size_t OBDI  = OBGHN + (size_t)2*7*256*4;
constexpr size_t OBDHN = OBDI + (size_t)21*256*4;
constexpr size_t OBWR  = OBDHN + (size_t)7*256*4;
constexpr size_t OBH   = OBWR + (size_t)49*256*4;
constexpr size_t OGH   = OBH + (size_t)14*256*4;             // Ghml bf16 [8192][256] (hmu|hlv padded)
constexpr size_t OGD   = OGH + (size_t)8192*512;             // Ghdec bf16 [8192][112]
constexpr size_t WSEND = OGD + (size_t)8192*224;             // ~20.1 MB

__device__ __forceinline__ float sigf(float x){ return 1.0f/(1.0f+__expf(-x)); }
__device__ __forceinline__ float tanhfast(float x){ return 1.0f - 2.0f/(__expf(2.0f*x)+1.0f); }
__device__ __forceinline__ float bf2f(unsigned short u){ return __uint_as_float(((unsigned int)u)<<16); }
__device__ __forceinline__ unsigned short f2bf(float f){ unsigned int x = __float_as_uint(f); return (unsigned short)((x + 0x8000u) >> 16); }

// ---------------- weight / bias packing + state zero ----------------
__global__ void init_pack(
    const float* __restrict__ ihmu, const float* __restrict__ whhmu,
    const float* __restrict__ bihmu, const float* __restrict__ bhhmu,
    const float* __restrict__ ihlv, const float* __restrict__ whhlv,
    const float* __restrict__ bihlv, const float* __restrict__ bhhlv,
    const float* __restrict__ wmu, const float* __restrict__ bmu,
    const float* __restrict__ wlv, const float* __restrict__ blv,
    const float* __restrict__ ihd, const float* __restrict__ whhd,
    const float* __restrict__ bihd, const float* __restrict__ bhhd,
    const float* __restrict__ wwr, const float* __restrict__ bwr,
    char* __restrict__ wsb)
{
  int u = blockIdx.x*256 + threadIdx.x;
  if (u < 1469440) {
    int v = u; size_t off; int NT; int region;
    if      (v < 537600)            { region=0; off=OWSUM; NT=42; }
    else if ((v-=537600) < 301056)  { region=1; off=OWEAM; NT=21; }
    else if ((v-=301056) < 301056)  { region=2; off=OWEAL; NT=21; }
    else if ((v-=301056) < 43008)   { region=3; off=OWEBM; NT=21; }
    else if ((v-=43008)  < 43008)   { region=4; off=OWEBL; NT=21; }
    else if ((v-=43008)  < 57344)   { region=5; off=OWH;   NT=14; }
    else if ((v-=57344)  < 86016)   { region=6; off=OWD;   NT=21; }
    else    { v-=86016;   region=7; off=OWW;   NT=49; }
    int ks = v / (NT*512); int rem = v - ks*(NT*512);
    int nt = rem >> 9; int li = rem & 511;
    int l = li >> 3, e = li & 7;
    int k = ks*32 + ((l>>4)<<3) + e;
    int c = l & 15;
    float val = 0.f;
    if (region==0) {
      int gru = nt/21, ntg = nt%21, gate = ntg/7, j = (ntg%7)*16 + c;
      if (j<100 && k<784) { const float* IH = gru? ihlv : ihmu; int jj = gate*100+j;
        val = IH[(size_t)jj*1668 + k] + IH[(size_t)jj*1668 + 784 + k]; }
    } else if (region==1 || region==2) {
      const float* IH = (region==2)? ihlv : ihmu;
      int gate = nt/7, j = (nt%7)*16 + c;
      if (j<100) { int jj = gate*100+j;
        if (k<784)      val = -IH[(size_t)jj*1668 + 784 + k];
        else if (k<884) val =  IH[(size_t)jj*1668 + 1568 + (k-784)]; }
    } else if (region==3 || region==4) {
      const float* WHH = (region==4)? whhlv : whhmu;
      int gate = nt/7, j = (nt%7)*16 + c;
      if (j<100 && k<100) val = WHH[(gate*100+j)*100 + k];
    } else if (region==5) {
      int grp = nt/7, j = (nt%7)*16 + c;
      if (j<100) {
        if (grp==0) { if (k<100) val = wmu[j*100+k]; }
        else        { if (k>=128 && k<228) val = wlv[j*100 + (k-128)]; }
      }
    } else if (region==6) {
      int gate = nt/7, j = (nt%7)*16 + c;
      if (j<100) { int jj = gate*100+j;
        if (k<100)               val = ihd[jj*100+k];
        else if (k>=128 && k<228) val = whhd[jj*100 + (k-128)]; }
    } else {
      int n = nt*16 + c;
      if (k<100) val = wwr[n*100+k];
    }
    *(unsigned short*)(wsb + off + (size_t)v*2) = f2bf(val);
    return;
  }
  u -= 1469440;
  if (u >= 37632) {
    int u2 = u - 37632;                     // zero Ghml + Ghdec (1,507,328 words)
    if (u2 < 1507328) *(float*)(wsb + OGH + (size_t)u2*4) = 0.f;
    return;
  }
  float val = 0.f; size_t off; int v = u;
  if (v < 10752) { off = OBP2;
    int nt = v>>8, li = v&255, l = li>>2, c = l&15;
    int gru = nt/21, ntg = nt%21, gate = ntg/7, j = (ntg%7)*16 + c;
    if (j<100) {
      const float* BI = gru? bihlv : bihmu; const float* BH = gru? bhhlv : bhhmu;
      val = BI[gate*100+j] + ((gate<2)? BH[gate*100+j] : 0.f);
    }
  } else if ((v-=10752) < 3584) { off = OBGHN;
    int g = v/1792, r2 = v - g*1792, pp = r2>>8, li = r2&255, l = li>>2, c = l&15;
    int j = pp*16+c;
    if (j<100) val = (g? bhhlv : bhhmu)[200+j];
  } else if ((v-=3584) < 5376) { off = OBDI;
    int nt = v>>8, li = v&255, l = li>>2, c = l&15;
    int gate = nt/7, j = (nt%7)*16+c;
    if (j<100) val = (gate<2)? (bihd[gate*100+j]+bhhd[gate*100+j]) : bihd[200+j];
  } else if ((v-=5376) < 1792) { off = OBDHN;
    int pp = v>>8, li = v&255, l = li>>2, c = l&15; int j = pp*16+c;
    if (j<100) val = bhhd[200+j];
  } else if ((v-=1792) < 12544) { off = OBWR;
    int nt = v>>8, li = v&255, l = li>>2, c = l&15;
    val = bwr[nt*16+c];
  } else { v -= 12544; off = OBH;
    int nt = v>>8, li = v&255, l = li>>2, c = l&15;
    int grp = nt/7, j = (nt%7)*16+c;
    if (j<100) val = grp? blv[j] : bmu[j];
  }
  *(float*)(wsb + off + (size_t)v*4) = val;
}

// zero canvas c (accumulated in out_c across 2-step launches)
__global__ void init_out(float* __restrict__ out)
{
  size_t i = (size_t)blockIdx.x*1024 + threadIdx.x;
  if (i < (size_t)8192*784) out[i] = 0.f;
}

// ---------------- P2 = x@(W1+W2)^T + bias -> bf16 fragments ----------------
__global__ __launch_bounds__(512) void init_p2(const float* __restrict__ x, char* __restrict__ wsb)
{
  __shared__ char xt[16*1600];
  const int tid = threadIdx.x, l = tid&63, w = tid>>6;
  const int lr = l&15, lg = l>>4;
  const int rt = blockIdx.x;
  for (int i = tid; i < 16*800; i += 512) {
    int row = i/800, col = i - row*800;
    unsigned short hv = 0;
    if (col < 784) hv = f2bf(x[(size_t)(rt*16+row)*784 + col]);
    *(unsigned short*)(xt + ((row*1600 + col*2) ^ ((row&7)<<4))) = hv;
  }
  __syncthreads();
  const char* WS = wsb + OWSUM;
  for (int nt = w; nt < 42; nt += 8) {
    f32x4 acc = *(const f32x4*)(wsb + OBP2 + (size_t)(nt*256 + l*4)*4);
    const char* wp = WS + (size_t)(nt*512 + l*8)*2;
    #pragma unroll 5
    for (int ks = 0; ks < 25; ++ks) {
      bf16x8 a = *(const bf16x8*)(xt + ((lr*1600 + ks*64 + lg*16) ^ ((lr&7)<<4)));
      bf16x8 b = *(const bf16x8*)(wp + (size_t)ks*42*512*2);
      acc = MFMA(a,b,acc);
    }
    ushort4 ov; ov.x=f2bf(acc[0]); ov.y=f2bf(acc[1]); ov.z=f2bf(acc[2]); ov.w=f2bf(acc[3]);
    *(ushort4*)(wsb + OP2 + ((size_t)(rt*42+nt)*64 + l)*8) = ov;
  }
}

// ------- 2-step kernel: 512 blocks x 1024 threads (16 waves), 16 rows, t0 and t0+1 -------
__global__ __launch_bounds__(1024,8) void draw_step2(
    const float* __restrict__ noise, char* __restrict__ wsb, float* __restrict__ out, int t0)
{
  extern __shared__ char sm[];
  char* Aenc = sm;               // [16][1792 B] bf16: sigc(784) | hdec(100) | pad
  char* Ahml = sm + 28672;       // [16][512 B]  bf16: hmu(100) pad | hlv(100) pad
  char* Adec = sm + 36864;       // [16][512 B]  bf16: z(100) pad | hdec(100) pad
  float* muv = (float*)(sm + 45056);   // [1600] mu | [1600] lv (f32)

  const int tid = threadIdx.x, l = tid&63, w = tid>>6;   // w in [0,16)
  const int lr = l&15, lg = l>>4;
  const int blk = blockIdx.x;

  float* out_c  = out;
  float* out_mu = out + (size_t)8192*784;
  float* out_lv = out_mu + (size_t)32*8192*100;

  // ===== phase 0: load state from global (once per launch) =====
  {
    const float* cb = out_c + (size_t)blk*16*784;
    for (int i = tid; i < 16*98; i += 1024) {
      int row = i/98, cc = i - row*98;
      f32x4 v0 = *(const f32x4*)(cb + (size_t)row*784 + cc*8);
      f32x4 v1 = *(const f32x4*)(cb + (size_t)row*784 + cc*8 + 4);
      unsigned short h[8];
      h[0]=f2bf(sigf(v0[0])); h[1]=f2bf(sigf(v0[1])); h[2]=f2bf(sigf(v0[2])); h[3]=f2bf(sigf(v0[3]));
      h[4]=f2bf(sigf(v1[0])); h[5]=f2bf(sigf(v1[1])); h[6]=f2bf(sigf(v1[2])); h[7]=f2bf(sigf(v1[3]));
      *(bf16x8*)(Aenc + ((row*1792 + cc*16) ^ ((row&7)<<4))) = *(bf16x8*)h;
    }
    // hdec chunks: into Aenc cols 784+ AND Adec bytes 256+
    for (int i = tid; i < 16*14; i += 1024) {
      int row = i/14, cc = i - row*14;
      f32x4 v = *(const f32x4*)(wsb + OGD + (size_t)(blk*16+row)*224 + cc*16);
      *(f32x4*)(Aenc + ((row*1792 + (98+cc)*16) ^ ((row&7)<<4))) = v;
      *(f32x4*)(Adec + ((row*512 + 256 + cc*16) ^ ((row&7)<<4))) = v;
    }
    // hml from Ghml
    for (int i = tid; i < 16*32; i += 1024) {
      int row = i/32, cc = i - row*32;
      f32x4 v = *(const f32x4*)(wsb + OGH + (size_t)(blk*16+row)*512 + cc*16);
      *(f32x4*)(Ahml + ((row*512 + cc*16) ^ ((row&7)<<4))) = v;
    }
    // zero Adec z-region (bytes 0..255) + tail chunks (bytes 480..511)
    const f32x4 zz = {0.f,0.f,0.f,0.f};
    for (int i = tid; i < 16*16; i += 1024) {
      int row = i/16, cc = i - row*16;
      *(f32x4*)(Adec + ((row*512 + cc*16) ^ ((row&7)<<4))) = zz;
    }
    for (int i = tid; i < 16*2; i += 1024) {
      int row = i/2, cc = 30 + (i&1);
      *(f32x4*)(Adec + ((row*512 + cc*16) ^ ((row&7)<<4))) = zz;
    }
  }

  const bool isMu = (w < 7);
  const bool isLv = (w >= 8 && w < 15);
  const bool act  = isMu || isLv;
  const int p = isMu ? w : (w - 8);
  const int axor = (lr&7)<<4;

  const f32x4 z4 = {0.f,0.f,0.f,0.f};
  __syncthreads();                         // B0: state staged

  for (int it = 0; it < 2; ++it) {
    const int t = t0 + it;

    // ---- noise prefetch ----
    float noz[2] = {0.f, 0.f};
    #pragma unroll
    for (int k2=0;k2<2;++k2) {
      int i = tid + k2*1024;
      if (i < 1600)
        noz[k2] = __builtin_nontemporal_load(noise + (size_t)t*819200 + (size_t)blk*1600 + i);
    }

    // ===== encoder GEMM =====
    f32x4 ar=z4, az=z4, an=z4, ahn=z4;
    if (act) {
      size_t pb = OP2 + (((size_t)blk*42 + (isLv?21:0) + p)*64 + l)*8;
      ushort4 pr = *(const ushort4*)(wsb + pb);
      ushort4 pz = *(const ushort4*)(wsb + pb + (size_t)7*64*8);
      ushort4 pn = *(const ushort4*)(wsb + pb + (size_t)14*64*8);
      ar[0]=bf2f(pr.x); ar[1]=bf2f(pr.y); ar[2]=bf2f(pr.z); ar[3]=bf2f(pr.w);
      az[0]=bf2f(pz.x); az[1]=bf2f(pz.y); az[2]=bf2f(pz.z); az[3]=bf2f(pz.w);
      an[0]=bf2f(pn.x); an[1]=bf2f(pn.y); an[2]=bf2f(pn.z); an[3]=bf2f(pn.w);
      ahn = *(const f32x4*)(wsb + OBGHN + (size_t)(((isLv?7:0)+p)*256 + l*4)*4);
      const char* wr = wsb + (isLv? OWEAL : OWEAM) + (size_t)(p*512 + l*8)*2;
      const char* wz = wr + (size_t)7*512*2;
      const char* wn = wr + (size_t)14*512*2;
      int abase = lr*1792 + lg*16;
      #pragma unroll 4
      for (int ks=0; ks<28; ++ks) {
        bf16x8 a = *(const bf16x8*)(Aenc + ((abase + ks*64) ^ axor));
        size_t so = (size_t)ks*21*512*2;
        ar = MFMA(a, *(const bf16x8*)(wr+so), ar);
        az = MFMA(a, *(const bf16x8*)(wz+so), az);
        an = MFMA(a, *(const bf16x8*)(wn+so), an);
      }
      const char* vr = wsb + (isLv? OWEBL : OWEBM) + (size_t)(p*512 + l*8)*2;
      const char* vz = vr + (size_t)7*512*2;
      const char* vn = vr + (size_t)14*512*2;
      int hb = lr*512 + (isLv?256:0) + lg*16;
      #pragma unroll
      for (int ks=0; ks<4; ++ks) {
        bf16x8 a = *(const bf16x8*)(Ahml + ((hb + ks*64) ^ axor));
        size_t so = (size_t)ks*21*512*2;
        ar  = MFMA(a, *(const bf16x8*)(vr+so), ar);
        az  = MFMA(a, *(const bf16x8*)(vz+so), az);
        ahn = MFMA(a, *(const bf16x8*)(vn+so), ahn);
      }
    }
    __syncthreads();                       // B1: Ahml reads done
    if (act) {
      int col = p*16 + lr;
      #pragma unroll
      for (int e=0;e<4;++e) {
        float rg = sigf(ar[e]);
        float zg = sigf(az[e]);
        float nn = tanhfast(fmaf(rg, ahn[e], an[e]));
        int row = lg*4 + e;
        if (col < 100) {
          size_t ha = (size_t)((row*512 + ((isLv?128:0)+col)*2) ^ ((row&7)<<4));
          float hold = bf2f(*(unsigned short*)(Ahml + ha));
          float hnew = nn + zg*(hold - nn);
          *(unsigned short*)(Ahml + ha) = f2bf(hnew);
        }
      }
    }
    __syncthreads();                       // B2: hmu/hlv ready

    // ===== heads =====
    if (isMu) {
      f32x4 am = *(const f32x4*)(wsb + OBH + (size_t)(p*256 + l*4)*4);
      const char* WH = wsb + OWH;
      int hb = lr*512 + lg*16;
      #pragma unroll
      for (int ks=0; ks<4; ++ks) {
        bf16x8 a0 = *(const bf16x8*)(Ahml + ((hb + ks*64) ^ axor));
        am = MFMA(a0, *(const bf16x8*)(WH + ((size_t)(ks*14+p)*512 + l*8)*2), am);
      }
      int col = p*16 + lr;
      if (col < 100) {
        #pragma unroll
        for (int e=0;e<4;++e)
          muv[(lg*4+e)*100 + col] = fmaxf(am[e], 0.f);
      }
    } else if (isLv) {
      f32x4 al = *(const f32x4*)(wsb + OBH + (size_t)((7+p)*256 + l*4)*4);
      const char* WH = wsb + OWH;
      int hb = lr*512 + 256 + lg*16;
      #pragma unroll
      for (int ks=0; ks<4; ++ks) {
        bf16x8 a1 = *(const bf16x8*)(Ahml + ((hb + ks*64) ^ axor));
        al = MFMA(a1, *(const bf16x8*)(WH + ((size_t)((ks+4)*14+7+p)*512 + l*8)*2), al);
      }
      int col = p*16 + lr;
      if (col < 100) {
        #pragma unroll
        for (int e=0;e<4;++e)
          muv[1600 + (lg*4+e)*100 + col] = fmaxf(al[e], 0.f);
      }
    }
    __syncthreads();                       // B3: muv complete

    // ===== z + mu/lv stores =====
    #pragma unroll
    for (int k2=0;k2<2;++k2) {
      int i = tid + k2*1024;
      if (i < 1600) {
        float m  = muv[i];
        float lv = muv[1600 + i];
        float zz = fmaf(noz[k2], __expf(0.5f*lv), m);
        int row = i/100, col = i - row*100;
        *(unsigned short*)(Adec + ((row*512 + col*2) ^ ((row&7)<<4))) = f2bf(zz);
      }
    }
    {
      size_t mb = (size_t)t*819200 + (size_t)blk*1600;
      if (tid < 800) {
        bool m0 = tid < 400;
        int k = m0 ? tid : tid - 400;
        f32x4 v = ((const f32x4*)muv)[tid];
        *((f32x4*)((m0 ? out_mu : out_lv) + mb) + k) = v;
      }
    }
    __syncthreads();                       // B4: Adec z ready

    // ===== decoder GRU =====
    f32x4 dr=z4, dz=z4, dn=z4, dhn=z4;
    if (isLv) {
      dr  = *(const f32x4*)(wsb + OBDI  + (size_t)(p*256 + l*4)*4);
      dz  = *(const f32x4*)(wsb + OBDI  + (size_t)((p+7)*256 + l*4)*4);
      dn  = *(const f32x4*)(wsb + OBDI  + (size_t)((p+14)*256 + l*4)*4);
      dhn = *(const f32x4*)(wsb + OBDHN + (size_t)(p*256 + l*4)*4);
      const char* br = wsb + OWD + (size_t)(p*512 + l*8)*2;
      const char* bz = br + (size_t)7*512*2;
      const char* bn = br + (size_t)14*512*2;
      int abase = lr*512 + lg*16;
      #pragma unroll
      for (int ks=0; ks<8; ++ks) {
        bf16x8 a = *(const bf16x8*)(Adec + ((abase + ks*64) ^ axor));
        size_t so = (size_t)ks*21*512*2;
        dr = MFMA(a, *(const bf16x8*)(br+so), dr);
        dz = MFMA(a, *(const bf16x8*)(bz+so), dz);
        if (ks<4) dn  = MFMA(a, *(const bf16x8*)(bn+so), dn);
        else      dhn = MFMA(a, *(const bf16x8*)(bn+so), dhn);
      }
    }
    __syncthreads();                       // B5: Adec reads done
    if (isLv) {
      int col = p*16 + lr;
      #pragma unroll
      for (int e=0;e<4;++e) {
        float rg = sigf(dr[e]);
        float zg = sigf(dz[e]);
        float nn = tanhfast(fmaf(rg, dhn[e], dn[e]));
        int row = lg*4 + e;
        if (col < 100) {
          float hold = bf2f(*(unsigned short*)(Aenc + ((row*1792 + (784+col)*2) ^ ((row&7)<<4))));
          float hnew = nn + zg*(hold - nn);
          unsigned short hb2 = f2bf(hnew);
          *(unsigned short*)(Adec + ((row*512 + (128+col)*2) ^ ((row&7)<<4))) = hb2;
          *(unsigned short*)(Aenc + ((row*1792 + (784+col)*2) ^ ((row&7)<<4))) = hb2;
        }
      }
    }
    __syncthreads();                       // B6: new hdec visible

    // ===== canvas write GEMM: RMW on out_c (no held registers); stage sigc for it=0 =====
    {
      const char* WW = wsb + OWW;
      #pragma unroll
      for (int rep=0; rep<4; ++rep) {
        int nt = w + rep*16;
        if (nt < 49) {
          f32x4 c = z4;
          int abase = lr*512 + 256 + lg*16;
          #pragma unroll
          for (int ks=0; ks<4; ++ks) {
            bf16x8 a = *(const bf16x8*)(Adec + ((abase + ks*64) ^ axor));
            c = MFMA(a, *(const bf16x8*)(WW + ((size_t)(ks*49+nt)*512 + l*8)*2), c);
          }
          f32x4 bw = *(const f32x4*)(wsb + OBWR + (size_t)(nt*256 + l*4)*4);
          #pragma unroll
          for (int e=0;e<4;++e) {
            int orow = lg*4 + e;
            int col = nt*16 + lr;
            size_t ci = (size_t)(blk*16+orow)*784 + col;
            float cnew = out_c[ci] + c[e] + bw[e];
            out_c[ci] = (t == 31) ? sigf(cnew) : cnew;
            if (it == 0 && t < 31)
              *(unsigned short*)(Aenc + ((orow*1792 + col*2) ^ ((orow&7)<<4))) = f2bf(sigf(cnew));
          }
        }
      }
    }
    __syncthreads();                       // B7: sigc/states ready for next step
  }

  // ===== epilogue: persist h-state for next launch (t0 < 30) =====
  if (t0 < 30) {
    for (int i = tid; i < 16*32; i += 1024) {
      int row = i/32, cc = i - row*32;
      *(f32x4*)(wsb + OGH + (size_t)(blk*16+row)*512 + cc*16) =
        *(const f32x4*)(Ahml + ((row*512 + cc*16) ^ ((row&7)<<4)));
    }
    for (int i = tid; i < 16*14; i += 1024) {
      int row = i/14, cc = i - row*14;
      *(f32x4*)(wsb + OGD + (size_t)(blk*16+row)*224 + cc*16) =
        *(const f32x4*)(Aenc + ((row*1792 + (98+cc)*16) ^ ((row&7)<<4)));
    }
  }
}

extern "C" void kernel_launch(void* const* d_in, const int* in_sizes, int n_in,
                              void* d_out, int out_size, void* d_ws, size_t ws_size,
                              hipStream_t stream) {
  (void)in_sizes; (void)n_in; (void)out_size; (void)ws_size;
  const float* x      = (const float*)d_in[0];
  const float* noise  = (const float*)d_in[1];
  const float* ih_mu  = (const float*)d_in[2];
  const float* whh_mu = (const float*)d_in[3];
  const float* bih_mu = (const float*)d_in[4];
  const float* bhh_mu = (const float*)d_in[5];
  const float* ih_lv  = (const float*)d_in[6];
  const float* whh_lv = (const float*)d_in[7];
  const float* bih_lv = (const float*)d_in[8];
  const float* bhh_lv = (const float*)d_in[9];
  const float* wmu    = (const float*)d_in[10];
  const float* bmu    = (const float*)d_in[11];
  const float* wlv    = (const float*)d_in[12];
  const float* blv    = (const float*)d_in[13];
  const float* wih_dec= (const float*)d_in[14];
  const float* whh_dec= (const float*)d_in[15];
  const float* bih_dec= (const float*)d_in[16];
  const float* bhh_dec= (const float*)d_in[17];
  const float* wwrite = (const float*)d_in[18];
  const float* bwrite = (const float*)d_in[19];
  char* wsb = (char*)d_ws;
  float* out = (float*)d_out;

  (void)hipFuncSetAttribute(reinterpret_cast<const void*>(draw_step2),
                            hipFuncAttributeMaxDynamicSharedMemorySize, 57856);

  init_pack<<<11775, 256, 0, stream>>>(ih_mu, whh_mu, bih_mu, bhh_mu,
                                       ih_lv, whh_lv, bih_lv, bhh_lv,
                                       wmu, bmu, wlv, blv,
                                       wih_dec, whh_dec, bih_dec, bhh_dec,
                                       wwrite, bwrite, wsb);
  init_out<<<6272, 1024, 0, stream>>>(out);
  init_p2<<<512, 512, 0, stream>>>(x, wsb);
  for (int t0 = 0; t0 < 32; t0 += 2)
    draw_step2<<<512, 1024, 57856, stream>>>(noise, wsb, out, t0);
}

// Round 21
// 1741.643 us; speedup vs baseline: 4.0294x; 3.6811x over previous
//
#include <hip/hip_runtime.h>
#include <cstdint>

typedef short bf16x8 __attribute__((ext_vector_type(8)));
typedef float f32x4 __attribute__((ext_vector_type(4)));

#define MFMA(a,b,c) __builtin_amdgcn_mfma_f32_16x16x32_bf16((a),(b),(c),0,0,0)

// ---------------- ws layout (bytes) ----------------
constexpr size_t OP2   = 0;                                  // P2 bf16 frags [512rt][42nt][64][4]
constexpr size_t SZP2  = (size_t)512*42*512;                 // 11,010,048
constexpr size_t OWSUM = OP2 + SZP2;                         // [25ks][42nt][512] bf16
constexpr size_t SZWSUM= (size_t)25*42*512*2;
constexpr size_t OWEAM = OWSUM + SZWSUM;                     // enc A-side mu [28][21][512]
constexpr size_t SZWEA = (size_t)28*21*512*2;
constexpr size_t OWEAL = OWEAM + SZWEA;
constexpr size_t OWEBM = OWEAL + SZWEA;                      // enc h-side [4][21][512]
constexpr size_t SZWEB = (size_t)4*21*512*2;
constexpr size_t OWEBL = OWEBM + SZWEB;
constexpr size_t OWH   = OWEBL + SZWEB;                      // heads [8][14][512]
constexpr size_t SZWH  = (size_t)8*14*512*2;
constexpr size_t OWD   = OWH + SZWH;                         // dec [8][21][512]
constexpr size_t SZWD  = (size_t)8*21*512*2;
constexpr size_t OWW   = OWD + SZWD;                         // write [4][49][512]
constexpr size_t SZWW  = (size_t)4*49*512*2;
constexpr size_t OBP2  = OWW + SZWW;                         // f32 bias frags
constexpr size_t OBGHN = OBP2 + (size_t)42*256*4;
constexpr size_t OBDI  = OBGHN + (size_t)2*7*256*4;
constexpr size_t OBDHN = OBDI + (size_t)21*256*4;
constexpr size_t OBWR  = OBDHN + (size_t)7*256*4;
constexpr size_t OBH   = OBWR + (size_t)49*256*4;
constexpr size_t OGH   = OBH + (size_t)14*256*4;             // Ghml bf16 [8192][256] (hmu|hlv padded)
constexpr size_t OGD   = OGH + (size_t)8192*512;             // Ghdec bf16 [8192][112]
constexpr size_t WSEND = OGD + (size_t)8192*224;             // ~20.1 MB

__device__ __forceinline__ float sigf(float x){ return 1.0f/(1.0f+__expf(-x)); }
__device__ __forceinline__ float tanhfast(float x){ return 1.0f - 2.0f/(__expf(2.0f*x)+1.0f); }
__device__ __forceinline__ float bf2f(unsigned short u){ return __uint_as_float(((unsigned int)u)<<16); }
__device__ __forceinline__ unsigned short f2bf(float f){ unsigned int x = __float_as_uint(f); return (unsigned short)((x + 0x8000u) >> 16); }

// ---------------- weight / bias packing ----------------
__global__ void init_pack(
    const float* __restrict__ ihmu, const float* __restrict__ whhmu,
    const float* __restrict__ bihmu, const float* __restrict__ bhhmu,
    const float* __restrict__ ihlv, const float* __restrict__ whhlv,
    const float* __restrict__ bihlv, const float* __restrict__ bhhlv,
    const float* __restrict__ wmu, const float* __restrict__ bmu,
    const float* __restrict__ wlv, const float* __restrict__ blv,
    const float* __restrict__ ihd, const float* __restrict__ whhd,
    const float* __restrict__ bihd, const float* __restrict__ bhhd,
    const float* __restrict__ wwr, const float* __restrict__ bwr,
    char* __restrict__ wsb)
{
  int u = blockIdx.x*256 + threadIdx.x;
  if (u < 1469440) {
    int v = u; size_t off; int NT; int region;
    if      (v < 537600)            { region=0; off=OWSUM; NT=42; }
    else if ((v-=537600) < 301056)  { region=1; off=OWEAM; NT=21; }
    else if ((v-=301056) < 301056)  { region=2; off=OWEAL; NT=21; }
    else if ((v-=301056) < 43008)   { region=3; off=OWEBM; NT=21; }
    else if ((v-=43008)  < 43008)   { region=4; off=OWEBL; NT=21; }
    else if ((v-=43008)  < 57344)   { region=5; off=OWH;   NT=14; }
    else if ((v-=57344)  < 86016)   { region=6; off=OWD;   NT=21; }
    else    { v-=86016;   region=7; off=OWW;   NT=49; }
    int ks = v / (NT*512); int rem = v - ks*(NT*512);
    int nt = rem >> 9; int li = rem & 511;
    int l = li >> 3, e = li & 7;
    int k = ks*32 + ((l>>4)<<3) + e;
    int c = l & 15;
    float val = 0.f;
    if (region==0) {
      int gru = nt/21, ntg = nt%21, gate = ntg/7, j = (ntg%7)*16 + c;
      if (j<100 && k<784) { const float* IH = gru? ihlv : ihmu; int jj = gate*100+j;
        val = IH[(size_t)jj*1668 + k] + IH[(size_t)jj*1668 + 784 + k]; }
    } else if (region==1 || region==2) {
      const float* IH = (region==2)? ihlv : ihmu;
      int gate = nt/7, j = (nt%7)*16 + c;
      if (j<100) { int jj = gate*100+j;
        if (k<784)      val = -IH[(size_t)jj*1668 + 784 + k];
        else if (k<884) val =  IH[(size_t)jj*1668 + 1568 + (k-784)]; }
    } else if (region==3 || region==4) {
      const float* WHH = (region==4)? whhlv : whhmu;
      int gate = nt/7, j = (nt%7)*16 + c;
      if (j<100 && k<100) val = WHH[(gate*100+j)*100 + k];
    } else if (region==5) {
      int grp = nt/7, j = (nt%7)*16 + c;
      if (j<100) {
        if (grp==0) { if (k<100) val = wmu[j*100+k]; }
        else        { if (k>=128 && k<228) val = wlv[j*100 + (k-128)]; }
      }
    } else if (region==6) {
      int gate = nt/7, j = (nt%7)*16 + c;
      if (j<100) { int jj = gate*100+j;
        if (k<100)               val = ihd[jj*100+k];
        else if (k>=128 && k<228) val = whhd[jj*100 + (k-128)]; }
    } else {
      int n = nt*16 + c;
      if (k<100) val = wwr[n*100+k];
    }
    *(unsigned short*)(wsb + off + (size_t)v*2) = f2bf(val);
    return;
  }
  u -= 1469440;
  if (u >= 37632) return;
  float val = 0.f; size_t off; int v = u;
  if (v < 10752) { off = OBP2;
    int nt = v>>8, li = v&255, l = li>>2, c = l&15;
    int gru = nt/21, ntg = nt%21, gate = ntg/7, j = (ntg%7)*16 + c;
    if (j<100) {
      const float* BI = gru? bihlv : bihmu; const float* BH = gru? bhhlv : bhhmu;
      val = BI[gate*100+j] + ((gate<2)? BH[gate*100+j] : 0.f);
    }
  } else if ((v-=10752) < 3584) { off = OBGHN;
    int g = v/1792, r2 = v - g*1792, pp = r2>>8, li = r2&255, l = li>>2, c = l&15;
    int j = pp*16+c;
    if (j<100) val = (g? bhhlv : bhhmu)[200+j];
  } else if ((v-=3584) < 5376) { off = OBDI;
    int nt = v>>8, li = v&255, l = li>>2, c = l&15;
    int gate = nt/7, j = (nt%7)*16+c;
    if (j<100) val = (gate<2)? (bihd[gate*100+j]+bhhd[gate*100+j]) : bihd[200+j];
  } else if ((v-=5376) < 1792) { off = OBDHN;
    int pp = v>>8, li = v&255, l = li>>2, c = l&15; int j = pp*16+c;
    if (j<100) val = bhhd[200+j];
  } else if ((v-=1792) < 12544) { off = OBWR;
    int nt = v>>8, li = v&255, l = li>>2, c = l&15;
    val = bwr[nt*16+c];
  } else { v -= 12544; off = OBH;
    int nt = v>>8, li = v&255, l = li>>2, c = l&15;
    int grp = nt/7, j = (nt%7)*16+c;
    if (j<100) val = grp? blv[j] : bmu[j];
  }
  *(float*)(wsb + off + (size_t)v*4) = val;
}

// ---------------- P2 = x@(W1+W2)^T + bias -> bf16 fragments ----------------
__global__ __launch_bounds__(512) void init_p2(const float* __restrict__ x, char* __restrict__ wsb)
{
  __shared__ char xt[16*1600];
  const int tid = threadIdx.x, l = tid&63, w = tid>>6;
  const int lr = l&15, lg = l>>4;
  const int rt = blockIdx.x;
  for (int i = tid; i < 16*800; i += 512) {
    int row = i/800, col = i - row*800;
    unsigned short hv = 0;
    if (col < 784) hv = f2bf(x[(size_t)(rt*16+row)*784 + col]);
    *(unsigned short*)(xt + ((row*1600 + col*2) ^ ((row&7)<<4))) = hv;
  }
  __syncthreads();
  const char* WS = wsb + OWSUM;
  for (int nt = w; nt < 42; nt += 8) {
    f32x4 acc = *(const f32x4*)(wsb + OBP2 + (size_t)(nt*256 + l*4)*4);
    const char* wp = WS + (size_t)(nt*512 + l*8)*2;
    #pragma unroll 5
    for (int ks = 0; ks < 25; ++ks) {
      bf16x8 a = *(const bf16x8*)(xt + ((lr*1600 + ks*64 + lg*16) ^ ((lr&7)<<4)));
      bf16x8 b = *(const bf16x8*)(wp + (size_t)ks*42*512*2);
      acc = MFMA(a,b,acc);
    }
    ushort4 ov; ov.x=f2bf(acc[0]); ov.y=f2bf(acc[1]); ov.z=f2bf(acc[2]); ov.w=f2bf(acc[3]);
    *(ushort4*)(wsb + OP2 + ((size_t)(rt*42+nt)*64 + l)*8) = ov;
  }
}

// ------- per-step kernel: 512 blocks x 1024 threads (16 waves), 16 rows -------
__global__ __launch_bounds__(1024,8) void draw_step(
    const float* __restrict__ noise, char* __restrict__ wsb, float* __restrict__ out, int t)
{
  extern __shared__ char sm[];
  char* Aenc = sm;               // [16][1792 B] bf16: sigc(784) | hdec(100) | pad
  char* Ahml = sm + 28672;       // [16][512 B]  bf16: hmu(100) pad | hlv(100) pad
  char* Adec = sm + 36864;       // [16][512 B]  bf16: z(100) pad | hdec(100) pad
  float* muv = (float*)(sm + 45056);   // [1600] mu | [1600] lv (f32)

  const int tid = threadIdx.x, l = tid&63, w = tid>>6;   // w in [0,16)
  const int lr = l&15, lg = l>>4;
  const int blk = blockIdx.x;

  float* out_c  = out;
  float* out_mu = out + (size_t)8192*784;
  float* out_lv = out_mu + (size_t)32*8192*100;

  // ===== phase 0: load state from global (t>0) or init constants (t==0) =====
  if (t == 0) {
    for (int i = tid; i < 16*112; i += 1024) {
      int row = i/112, cc = i - row*112;
      unsigned short fv = (cc < 98) ? (unsigned short)0x3F00 : (unsigned short)0;
      unsigned short h[8] = {fv,fv,fv,fv,fv,fv,fv,fv};
      *(bf16x8*)(Aenc + ((row*1792 + cc*16) ^ ((row&7)<<4))) = *(bf16x8*)h;
    }
    const f32x4 zz = {0.f,0.f,0.f,0.f};
    for (int i = tid; i < 16*32; i += 1024) {
      int row = i/32, cc = i - row*32;
      *(f32x4*)(Ahml + ((row*512 + cc*16) ^ ((row&7)<<4))) = zz;
      *(f32x4*)(Adec + ((row*512 + cc*16) ^ ((row&7)<<4))) = zz;
    }
  } else {
    const float* cb = out_c + (size_t)blk*16*784;
    for (int i = tid; i < 16*98; i += 1024) {
      int row = i/98, cc = i - row*98;
      f32x4 v0 = *(const f32x4*)(cb + (size_t)row*784 + cc*8);
      f32x4 v1 = *(const f32x4*)(cb + (size_t)row*784 + cc*8 + 4);
      unsigned short h[8];
      h[0]=f2bf(sigf(v0[0])); h[1]=f2bf(sigf(v0[1])); h[2]=f2bf(sigf(v0[2])); h[3]=f2bf(sigf(v0[3]));
      h[4]=f2bf(sigf(v1[0])); h[5]=f2bf(sigf(v1[1])); h[6]=f2bf(sigf(v1[2])); h[7]=f2bf(sigf(v1[3]));
      *(bf16x8*)(Aenc + ((row*1792 + cc*16) ^ ((row&7)<<4))) = *(bf16x8*)h;
    }
    for (int i = tid; i < 16*14; i += 1024) {
      int row = i/14, cc = i - row*14;
      f32x4 v = *(const f32x4*)(wsb + OGD + (size_t)(blk*16+row)*224 + cc*16);
      *(f32x4*)(Aenc + ((row*1792 + (98+cc)*16) ^ ((row&7)<<4))) = v;
      *(f32x4*)(Adec + ((row*512 + 256 + cc*16) ^ ((row&7)<<4))) = v;
    }
    for (int i = tid; i < 16*32; i += 1024) {
      int row = i/32, cc = i - row*32;
      f32x4 v = *(const f32x4*)(wsb + OGH + (size_t)(blk*16+row)*512 + cc*16);
      *(f32x4*)(Ahml + ((row*512 + cc*16) ^ ((row&7)<<4))) = v;
    }
    const f32x4 zz = {0.f,0.f,0.f,0.f};
    for (int i = tid; i < 16*16; i += 1024) {
      int row = i/16, cc = i - row*16;
      *(f32x4*)(Adec + ((row*512 + cc*16) ^ ((row&7)<<4))) = zz;
    }
    for (int i = tid; i < 16*2; i += 1024) {
      int row = i/2, cc = 30 + (i&1);
      *(f32x4*)(Adec + ((row*512 + cc*16) ^ ((row&7)<<4))) = zz;
    }
  }

  const bool isMu = (w < 7);
  const bool isLv = (w >= 8 && w < 15);
  const bool act  = isMu || isLv;
  const int p = isMu ? w : (w - 8);
  const int axor = (lr&7)<<4;

  const f32x4 z4 = {0.f,0.f,0.f,0.f};
  __syncthreads();                         // B0: state staged

  // ---- noise prefetch ----
  float noz[2] = {0.f, 0.f};
  #pragma unroll
  for (int k2=0;k2<2;++k2) {
    int i = tid + k2*1024;
    if (i < 1600)
      noz[k2] = __builtin_nontemporal_load(noise + (size_t)t*819200 + (size_t)blk*1600 + i);
  }

  // ===== encoder GEMM =====
  f32x4 ar=z4, az=z4, an=z4, ahn=z4;
  if (act) {
    size_t pb = OP2 + (((size_t)blk*42 + (isLv?21:0) + p)*64 + l)*8;
    ushort4 pr = *(const ushort4*)(wsb + pb);
    ushort4 pz = *(const ushort4*)(wsb + pb + (size_t)7*64*8);
    ushort4 pn = *(const ushort4*)(wsb + pb + (size_t)14*64*8);
    ar[0]=bf2f(pr.x); ar[1]=bf2f(pr.y); ar[2]=bf2f(pr.z); ar[3]=bf2f(pr.w);
    az[0]=bf2f(pz.x); az[1]=bf2f(pz.y); az[2]=bf2f(pz.z); az[3]=bf2f(pz.w);
    an[0]=bf2f(pn.x); an[1]=bf2f(pn.y); an[2]=bf2f(pn.z); an[3]=bf2f(pn.w);
    ahn = *(const f32x4*)(wsb + OBGHN + (size_t)(((isLv?7:0)+p)*256 + l*4)*4);
    const char* wr = wsb + (isLv? OWEAL : OWEAM) + (size_t)(p*512 + l*8)*2;
    const char* wz = wr + (size_t)7*512*2;
    const char* wn = wr + (size_t)14*512*2;
    int abase = lr*1792 + lg*16;
    #pragma unroll 4
    for (int ks=0; ks<28; ++ks) {
      bf16x8 a = *(const bf16x8*)(Aenc + ((abase + ks*64) ^ axor));
      size_t so = (size_t)ks*21*512*2;
      ar = MFMA(a, *(const bf16x8*)(wr+so), ar);
      az = MFMA(a, *(const bf16x8*)(wz+so), az);
      an = MFMA(a, *(const bf16x8*)(wn+so), an);
    }
    const char* vr = wsb + (isLv? OWEBL : OWEBM) + (size_t)(p*512 + l*8)*2;
    const char* vz = vr + (size_t)7*512*2;
    const char* vn = vr + (size_t)14*512*2;
    int hb = lr*512 + (isLv?256:0) + lg*16;
    #pragma unroll
    for (int ks=0; ks<4; ++ks) {
      bf16x8 a = *(const bf16x8*)(Ahml + ((hb + ks*64) ^ axor));
      size_t so = (size_t)ks*21*512*2;
      ar  = MFMA(a, *(const bf16x8*)(vr+so), ar);
      az  = MFMA(a, *(const bf16x8*)(vz+so), az);
      ahn = MFMA(a, *(const bf16x8*)(vn+so), ahn);
    }
  }
  __syncthreads();                       // B1: Ahml reads done
  if (act) {
    int col = p*16 + lr;
    #pragma unroll
    for (int e=0;e<4;++e) {
      float rg = sigf(ar[e]);
      float zg = sigf(az[e]);
      float nn = tanhfast(fmaf(rg, ahn[e], an[e]));
      int row = lg*4 + e;
      if (col < 100) {
        size_t ha = (size_t)((row*512 + ((isLv?128:0)+col)*2) ^ ((row&7)<<4));
        float hold = bf2f(*(unsigned short*)(Ahml + ha));
        float hnew = nn + zg*(hold - nn);
        *(unsigned short*)(Ahml + ha) = f2bf(hnew);
      }
    }
  }
  __syncthreads();                       // B2: hmu/hlv ready

  // ===== heads =====
  if (isMu) {
    f32x4 am = *(const f32x4*)(wsb + OBH + (size_t)(p*256 + l*4)*4);
    const char* WH = wsb + OWH;
    int hb = lr*512 + lg*16;
    #pragma unroll
    for (int ks=0; ks<4; ++ks) {
      bf16x8 a0 = *(const bf16x8*)(Ahml + ((hb + ks*64) ^ axor));
      am = MFMA(a0, *(const bf16x8*)(WH + ((size_t)(ks*14+p)*512 + l*8)*2), am);
    }
    int col = p*16 + lr;
    if (col < 100) {
      #pragma unroll
      for (int e=0;e<4;++e)
        muv[(lg*4+e)*100 + col] = fmaxf(am[e], 0.f);
    }
  } else if (isLv) {
    f32x4 al = *(const f32x4*)(wsb + OBH + (size_t)((7+p)*256 + l*4)*4);
    const char* WH = wsb + OWH;
    int hb = lr*512 + 256 + lg*16;
    #pragma unroll
    for (int ks=0; ks<4; ++ks) {
      bf16x8 a1 = *(const bf16x8*)(Ahml + ((hb + ks*64) ^ axor));
      al = MFMA(a1, *(const bf16x8*)(WH + ((size_t)((ks+4)*14+7+p)*512 + l*8)*2), al);
    }
    int col = p*16 + lr;
    if (col < 100) {
      #pragma unroll
      for (int e=0;e<4;++e)
        muv[1600 + (lg*4+e)*100 + col] = fmaxf(al[e], 0.f);
    }
  }
  __syncthreads();                       // B3: muv complete

  // ===== z + mu/lv stores =====
  #pragma unroll
  for (int k2=0;k2<2;++k2) {
    int i = tid + k2*1024;
    if (i < 1600) {
      float m  = muv[i];
      float lv = muv[1600 + i];
      float zz = fmaf(noz[k2], __expf(0.5f*lv), m);
      int row = i/100, col = i - row*100;
      *(unsigned short*)(Adec + ((row*512 + col*2) ^ ((row&7)<<4))) = f2bf(zz);
    }
  }
  {
    size_t mb = (size_t)t*819200 + (size_t)blk*1600;
    if (tid < 800) {
      bool m0 = tid < 400;
      int k = m0 ? tid : tid - 400;
      f32x4 v = ((const f32x4*)muv)[tid];
      *((f32x4*)((m0 ? out_mu : out_lv) + mb) + k) = v;
    }
  }
  __syncthreads();                       // B4: Adec z ready (hdec staged in phase 0)

  // ===== decoder GRU =====
  f32x4 dr=z4, dz=z4, dn=z4, dhn=z4;
  if (isLv) {
    dr  = *(const f32x4*)(wsb + OBDI  + (size_t)(p*256 + l*4)*4);
    dz  = *(const f32x4*)(wsb + OBDI  + (size_t)((p+7)*256 + l*4)*4);
    dn  = *(const f32x4*)(wsb + OBDI  + (size_t)((p+14)*256 + l*4)*4);
    dhn = *(const f32x4*)(wsb + OBDHN + (size_t)(p*256 + l*4)*4);
    const char* br = wsb + OWD + (size_t)(p*512 + l*8)*2;
    const char* bz = br + (size_t)7*512*2;
    const char* bn = br + (size_t)14*512*2;
    int abase = lr*512 + lg*16;
    #pragma unroll
    for (int ks=0; ks<8; ++ks) {
      bf16x8 a = *(const bf16x8*)(Adec + ((abase + ks*64) ^ axor));
      size_t so = (size_t)ks*21*512*2;
      dr = MFMA(a, *(const bf16x8*)(br+so), dr);
      dz = MFMA(a, *(const bf16x8*)(bz+so), dz);
      if (ks<4) dn  = MFMA(a, *(const bf16x8*)(bn+so), dn);
      else      dhn = MFMA(a, *(const bf16x8*)(bn+so), dhn);
    }
  }
  __syncthreads();                       // B5: Adec reads done
  if (isLv) {
    int col = p*16 + lr;
    #pragma unroll
    for (int e=0;e<4;++e) {
      float rg = sigf(dr[e]);
      float zg = sigf(dz[e]);
      float nn = tanhfast(fmaf(rg, dhn[e], dn[e]));
      int row = lg*4 + e;
      if (col < 100) {
        float hold = bf2f(*(unsigned short*)(Aenc + ((row*1792 + (784+col)*2) ^ ((row&7)<<4))));
        float hnew = nn + zg*(hold - nn);
        unsigned short hb2 = f2bf(hnew);
        *(unsigned short*)(Adec + ((row*512 + (128+col)*2) ^ ((row&7)<<4))) = hb2;
        *(unsigned short*)(Aenc + ((row*1792 + (784+col)*2) ^ ((row&7)<<4))) = hb2;
      }
    }
  }
  __syncthreads();                       // B6: new hdec visible

  // ===== save state (t<31) + canvas write GEMM with c-RMW in out_c =====
  if (t < 31) {
    for (int i = tid; i < 16*32; i += 1024) {
      int row = i/32, cc = i - row*32;
      *(f32x4*)(wsb + OGH + (size_t)(blk*16+row)*512 + cc*16) =
        *(const f32x4*)(Ahml + ((row*512 + cc*16) ^ ((row&7)<<4)));
    }
    for (int i = tid; i < 16*14; i += 1024) {
      int row = i/14, cc = i - row*14;
      *(f32x4*)(wsb + OGD + (size_t)(blk*16+row)*224 + cc*16) =
        *(const f32x4*)(Aenc + ((row*1792 + (98+cc)*16) ^ ((row&7)<<4)));
    }
  }
  {
    const char* WW = wsb + OWW;
    #pragma unroll
    for (int rep=0; rep<4; ++rep) {
      int nt = w + rep*16;
      if (nt < 49) {
        f32x4 c = z4;
        int abase = lr*512 + 256 + lg*16;
        #pragma unroll
        for (int ks=0; ks<4; ++ks) {
          bf16x8 a = *(const bf16x8*)(Adec + ((abase + ks*64) ^ axor));
          c = MFMA(a, *(const bf16x8*)(WW + ((size_t)(ks*49+nt)*512 + l*8)*2), c);
        }
        f32x4 bw = *(const f32x4*)(wsb + OBWR + (size_t)(nt*256 + l*4)*4);
        #pragma unroll
        for (int e=0;e<4;++e) {
          int orow = lg*4 + e;
          int col = nt*16 + lr;
          size_t ci = (size_t)(blk*16+orow)*784 + col;
          float cold = (t == 0) ? 0.f : out_c[ci];
          float cnew = cold + c[e] + bw[e];
          out_c[ci] = (t == 31) ? sigf(cnew) : cnew;
        }
      }
    }
  }
}

extern "C" void kernel_launch(void* const* d_in, const int* in_sizes, int n_in,
                              void* d_out, int out_size, void* d_ws, size_t ws_size,
                              hipStream_t stream) {
  (void)in_sizes; (void)n_in; (void)out_size; (void)ws_size;
  const float* x      = (const float*)d_in[0];
  const float* noise  = (const float*)d_in[1];
  const float* ih_mu  = (const float*)d_in[2];
  const float* whh_mu = (const float*)d_in[3];
  const float* bih_mu = (const float*)d_in[4];
  const float* bhh_mu = (const float*)d_in[5];
  const float* ih_lv  = (const float*)d_in[6];
  const float* whh_lv = (const float*)d_in[7];
  const float* bih_lv = (const float*)d_in[8];
  const float* bhh_lv = (const float*)d_in[9];
  const float* wmu    = (const float*)d_in[10];
  const float* bmu    = (const float*)d_in[11];
  const float* wlv    = (const float*)d_in[12];
  const float* blv    = (const float*)d_in[13];
  const float* wih_dec= (const float*)d_in[14];
  const float* whh_dec= (const float*)d_in[15];
  const float* bih_dec= (const float*)d_in[16];
  const float* bhh_dec= (const float*)d_in[17];
  const float* wwrite = (const float*)d_in[18];
  const float* bwrite = (const float*)d_in[19];
  char* wsb = (char*)d_ws;
  float* out = (float*)d_out;

  (void)hipFuncSetAttribute(reinterpret_cast<const void*>(draw_step),
                            hipFuncAttributeMaxDynamicSharedMemorySize, 57856);

  init_pack<<<5888, 256, 0, stream>>>(ih_mu, whh_mu, bih_mu, bhh_mu,
                                      ih_lv, whh_lv, bih_lv, bhh_lv,
                                      wmu, bmu, wlv, blv,
                                      wih_dec, whh_dec, bih_dec, bhh_dec,
                                      wwrite, bwrite, wsb);
  init_p2<<<512, 512, 0, stream>>>(x, wsb);
  for (int t = 0; t < 32; ++t)
    draw_step<<<512, 1024, 57856, stream>>>(noise, wsb, out, t);
}